// Round 6
// baseline (856.582 us; speedup 1.0000x reference)
//
#include <hip/hip_runtime.h>
#include <math.h>

#define B 32
#define V 16
#define T 64
#define F 64
#define H 512
#define NB 36
#define G4H 2048

typedef unsigned short u16;
typedef unsigned long long ull;
typedef __attribute__((ext_vector_type(8))) short bf16x8;
typedef __attribute__((ext_vector_type(4))) float f32x4;

// workspace offsets (float units)
#define OFF_H0     0           // 262144
#define OFF_H1     262144      // 262144
#define OFF_C      524288      // 262144
#define OFF_CNT    786432      // 32768 words: flag slots, 64B padded
#define OFF_WALL   819200      // 524288 fp32 w_all; ctx/hsoft alias (dead after recur)
#define OFF_CTX    819200      // 262144 (alias; written only after full rdone barrier)
#define OFF_HSOFT  1081344     // 262144 (alias; written only after full rdone barrier)
#define OFF_WMAX   1343488     // 64
#define OFF_WHSTG  1343552     // 262144 fl = 2 parities x 262144 u16 (wh, A-frag bf16)
#define OFF_SEQSTG 1605696     // 1064960 fl = 2129920 u16 (seq all t + denorm t=64, A-frag)
#define OFF_WSTG   2670656     // 9437184 fl (weights, B-frag bf16)
#define OFF_ENC    12107840    // 8388608 fl = 16777216 u16 (enc bf16)
// total 20,496,448 fl = 82.0 MB

#define WHP 262144   // u16 per whstg parity
#define WLDS_BYTES 147456  // 144 KB per-block weight slice (dynamic LDS)

__device__ __forceinline__ float sigmoidf_(float x) { return 1.0f / (1.0f + __expf(-x)); }

__device__ __forceinline__ u16 f2bf(float f) {  // RNE fp32->bf16
    union { float f; unsigned u; } x; x.f = f;
    unsigned r = x.u + 0x7FFF + ((x.u >> 16) & 1);
    return (u16)(r >> 16);
}
__device__ __forceinline__ float bf2f(u16 u) {
    union { unsigned i; float f; } x; x.i = ((unsigned)u) << 16;
    return x.f;
}
__device__ __forceinline__ f32x4 mfma16(bf16x8 a, bf16x8 b, f32x4 c) {
    return __builtin_amdgcn_mfma_f32_16x16x32_bf16(a, b, c, 0, 0, 0);
}
__device__ __forceinline__ bf16x8 mk_bf16x8(ull lo, ull hi) {
    union { ull u[2]; bf16x8 v; } x; x.u[0] = lo; x.u[1] = hi; return x.v;
}
__device__ __forceinline__ bf16x8 mk_bf16x8q(uint4 q) {
    union { uint4 q; bf16x8 v; } x; x.q = q; return x.v;
}

// device-scope coherent accesses (serviced at coherence point; no fences)
__device__ __forceinline__ ull ld_agent(const ull* p) {
    return __hip_atomic_load((ull*)p, __ATOMIC_RELAXED, __HIP_MEMORY_SCOPE_AGENT);
}
__device__ __forceinline__ void st_agent(ull* p, ull x) {
    __hip_atomic_store(p, x, __ATOMIC_RELAXED, __HIP_MEMORY_SCOPE_AGENT);
}
__device__ __forceinline__ void st_agent_f(float* p, float x) {
    __hip_atomic_store(p, x, __ATOMIC_RELAXED, __HIP_MEMORY_SCOPE_AGENT);
}
__device__ __forceinline__ void st_agent_u16(u16* p, u16 x) {
    __hip_atomic_store(p, x, __ATOMIC_RELAXED, __HIP_MEMORY_SCOPE_AGENT);
}
__device__ __forceinline__ void st_agent_u32(unsigned* p, unsigned x) {
    __hip_atomic_store(p, x, __ATOMIC_RELAXED, __HIP_MEMORY_SCOPE_AGENT);
}
__device__ __forceinline__ unsigned ld_agent_u32(const unsigned* p) {
    return __hip_atomic_load((unsigned*)p, __ATOMIC_RELAXED, __HIP_MEMORY_SCOPE_AGENT);
}

// ---------------------------------------------------------------------------
// Fused one-time preprocessing: [0,3200)=zero, [3200,3264)=hw_all,
// [3264,7872)=wconv, [7872,8912)=seqstg.  All four jobs are independent.
#define NZB 3200
#define NHW 64
#define NWC 4608
#define NSS 1040
__global__ __launch_bounds__(256) void k_prep(
    float* __restrict__ ws,
    const float* __restrict__ dist, const int* __restrict__ rb,
    const int* __restrict__ cog, const float* __restrict__ mask,
    const float* __restrict__ domain, float* __restrict__ w_all,
    float* __restrict__ wmax_all,
    const float* __restrict__ W_ih, const float* __restrict__ W_hh,
    u16* __restrict__ Wstg,
    const float* __restrict__ seq, const float* __restrict__ maxval,
    const float* __restrict__ minval, u16* __restrict__ seqstg) {
    __shared__ float red[256];
    int bid = blockIdx.x;
    int tid = threadIdx.x;

    if (bid < NZB) {
        // ---- zero h0,h1,c + flag slots: [0, 819200)
        ws[bid * 256 + tid] = 0.0f;
        return;
    }
    if (bid < NZB + NHW) {
        // ---- hardwired weights for all t
        int t = bid - NZB;
        float lmax = 0.0f;
        for (int idx = tid; idx < B * V * V; idx += 256) {
            int b = idx >> 8;
            int rem = idx & 255;
            int i = rem >> 4, j = rem & 15;
            int base = ((b * V + i) * T + t) * V + j;
            float val = domain[cog[base] * NB + rb[base]] - dist[base];
            val = val > 0.0f ? val : 0.0f;
            val *= mask[(b * V + i) * T + t] * mask[(b * V + j) * T + t];
            w_all[t * (B * V * V) + idx] = val;
            lmax = fmaxf(lmax, val);
        }
        red[tid] = lmax;
        __syncthreads();
        for (int s = 128; s > 0; s >>= 1) {
            if (tid < s) red[tid] = fmaxf(red[tid], red[tid + s]);
            __syncthreads();
        }
        if (tid == 0) wmax_all[t] = red[0];
        return;
    }
    if (bid < NZB + NHW + NWC) {
        // ---- W_ih||W_hh (fp32, K-minor) -> bf16 B-fragment layout
        // Wstg[v][hk16][ks18][nt8][lane64][8]; nt=g*2+hh
        int idx = bid - (NZB + NHW);
        int v = idx / 288, hk = (idx / 18) & 15, ks = idx % 18;
#pragma unroll
        for (int s = 0; s < 2; ++s) {
            int slot = tid + s * 256;
            int nt = slot >> 6, lane = slot & 63;
            int g = nt >> 1, hh = nt & 1;
            int col = g * H + hk * 32 + hh * 16 + (lane & 15);
            int k = ks * 32 + ((lane >> 4) << 3);
            const float* src = (k < F) ? &W_ih[(v * G4H + col) * F + k]
                                       : &W_hh[(v * G4H + col) * H + (k - F)];
            float4 x0 = *(const float4*)src;
            float4 x1 = *(const float4*)(src + 4);
            union { u16 u[8]; uint4 q; } pk;
            pk.u[0] = f2bf(x0.x); pk.u[1] = f2bf(x0.y); pk.u[2] = f2bf(x0.z); pk.u[3] = f2bf(x0.w);
            pk.u[4] = f2bf(x1.x); pk.u[5] = f2bf(x1.y); pk.u[6] = f2bf(x1.z); pk.u[7] = f2bf(x1.w);
            *(uint4*)&Wstg[(size_t)((((v * 16 + hk) * 18 + ks) * 8 + nt) * 64 + lane) * 8] = pk.q;
        }
        return;
    }
    {
        // ---- pack seq (t=64 = denormalized last input) into A-frag bf16:
        // seqstg[t][v][mt2][ks2][lane64][8]
        int idx = bid - (NZB + NHW + NWC);
        int v = idx / 65, t = idx % 65;
        int mt = tid >> 7, ks = (tid >> 6) & 1, lane = tid & 63;
        int b = mt * 16 + (lane & 15);
        int f = ks * 32 + ((lane >> 4) << 3);
        union { u16 u[8]; uint4 q; } pk;
        if (t < T) {
            const float* sp = &seq[((b * V + v) * T + t) * F + f];
            float4 x0 = *(const float4*)sp, x1 = *(const float4*)(sp + 4);
            pk.u[0] = f2bf(x0.x); pk.u[1] = f2bf(x0.y); pk.u[2] = f2bf(x0.z); pk.u[3] = f2bf(x0.w);
            pk.u[4] = f2bf(x1.x); pk.u[5] = f2bf(x1.y); pk.u[6] = f2bf(x1.z); pk.u[7] = f2bf(x1.w);
        } else {
            const float* sp = &seq[((b * V + v) * T + (T - 1)) * F + f];
            float4 x0 = *(const float4*)sp, x1 = *(const float4*)(sp + 4);
            float4 mx0 = *(const float4*)&maxval[b * F + f], mx1 = *(const float4*)&maxval[b * F + f + 4];
            float4 mn0 = *(const float4*)&minval[b * F + f], mn1 = *(const float4*)&minval[b * F + f + 4];
            pk.u[0] = f2bf(x0.x * (mx0.x - mn0.x) + mn0.x);
            pk.u[1] = f2bf(x0.y * (mx0.y - mn0.y) + mn0.y);
            pk.u[2] = f2bf(x0.z * (mx0.z - mn0.z) + mn0.z);
            pk.u[3] = f2bf(x0.w * (mx0.w - mn0.w) + mn0.w);
            pk.u[4] = f2bf(x1.x * (mx1.x - mn1.x) + mn1.x);
            pk.u[5] = f2bf(x1.y * (mx1.y - mn1.y) + mn1.y);
            pk.u[6] = f2bf(x1.z * (mx1.z - mn1.z) + mn1.z);
            pk.u[7] = f2bf(x1.w * (mx1.w - mn1.w) + mn1.w);
        }
        *(uint4*)&seqstg[(((size_t)(t * 16 + v)) * 4 + mt * 2 + ks) * 512 + lane * 8] = pk.q;
    }
}

// ---------------------------------------------------------------------------
// Persistent k_main R13 = R12 recurrence (verbatim sync structure, 498 us)
// + fused tail (attn + soft + out) with flag hops, replacing 3 launches.
// Cross-block data INSIDE one kernel needs agent scope both sides (per-XCD
// L2 non-coherence; no reliance on bid->XCD placement):
//   enc:  st_agent_u16 (recur) -> ld_agent (attn)
//   h:    st_agent_f (recur)   -> ld_agent (attn hs / soft hdec)
//   ctx:  st_agent (attn)      -> ld_agent (soft)   [aliases w_all!]
//   hsoft:st_agent_f (soft)    -> ld_agent (out)    [aliases w_all!]
// w_all-alias safety: full 256-block rdone barrier between recurrence and any
// ctx/hsoft write (w_all globally dead after it).
// Tail flags (prep zeroes them): rdone slot 512+bid; cflag 768+bid (attn
// done); sflag 1024+bid (soft done).  soft(v) waits cflag of the 16 attn
// blocks ≡v (mod 16); out(v) waits sflag of the 16 soft blocks ≡v (mod 16).
__global__ __launch_bounds__(256) void k_main(
    const u16* __restrict__ seqstg, const u16* __restrict__ Wstg,
    const float* __restrict__ w_all, const float* __restrict__ wmax_all,
    const float* __restrict__ b_ih, const float* __restrict__ b_hh,
    float* __restrict__ h0buf, float* __restrict__ h1buf,
    float* __restrict__ c, u16* __restrict__ enc, u16* __restrict__ whstg,
    unsigned* __restrict__ bar,
    const float* __restrict__ mask, const float* __restrict__ soft_W,
    const float* __restrict__ soft_b, const float* __restrict__ out_W,
    const float* __restrict__ out_b, float* __restrict__ ctx,
    float* __restrict__ hsoft, float* __restrict__ out) {
    extern __shared__ u16 Wlds[];          // 144 KB weight slice
    __shared__ float hs[H];                // attn scratch (2 KB)
    __shared__ float scal[2 * T];          // attn scores + alphas (0.5 KB)
    __shared__ float sA[32][36];           // soft tiles (4.5 KB)
    __shared__ float sW2[32][36];          // soft tiles (4.5 KB)

    int bid = blockIdx.x;
    int v = bid & 15, hk = bid >> 4;
    int tid = threadIdx.x;

    // ---- one-time: pin weight slice in LDS
    {
        const uint4* wsrc = (const uint4*)(Wstg + (size_t)((v * 16 + hk) * 18) * 4096);
        uint4* wdst = (uint4*)Wlds;
        for (int i = tid; i < 9216; i += 256) wdst[i] = wsrc[i];
    }

    int lane = tid & 63, wvi = tid >> 6;
    int mtw = wvi & 1, hh = wvi >> 1;
    int col = hk * 32 + hh * 16 + (lane & 15);
    int q4 = (lane >> 4) << 2;
    float bi = b_ih[v * G4H + col] + b_hh[v * G4H + col];
    float bf_ = b_ih[v * G4H + H + col] + b_hh[v * G4H + H + col];
    float bg_ = b_ih[v * G4H + 2 * H + col] + b_hh[v * G4H + 2 * H + col];
    float bo = b_ih[v * G4H + 3 * H + col] + b_hh[v * G4H + 3 * H + col];

    // flag slots: 64B padded.  aflag slot (v*16+hk); bflag slot 256+(hk*16+v)
    unsigned* aslot = bar + (v * 16 + hk) * 16;
    unsigned* bslot = bar + (256 + hk * 16 + v) * 16;
    unsigned* apoll = bar + (v * 16 + (tid & 15)) * 16;          // B-wait family v
    unsigned* bpoll = bar + (256 + hk * 16 + (tid & 15)) * 16;   // A-wait family hk

    // phase-A thread map: thread = (b = tid>>3, colq = tid&7)
    int a_b = tid >> 3;
    int a_cq = tid & 7;
    const int wh_idx = ((((v * 2 + (a_b >> 4)) * 16 + hk) * 64 +
                         (((a_cq >> 1) << 4) + (a_b & 15))) * 8 + (a_cq & 1) * 4);

    __syncthreads();  // W-LDS fill complete

    for (int t = 0; t <= T; ++t) {
        int par = t & 1;
        int tm = t < T ? t : (T - 1);
        const float* hin = (t & 1) ? h0buf : h1buf;
        float* hout = (t & 1) ? h1buf : h0buf;

        // ---- pre-wait independent work ------------------------------------
        uint4 s0 = *(const uint4*)&seqstg[(((size_t)(t * 16 + v)) * 4 + mtw * 2 + 0) * 512 + lane * 8];
        uint4 s1 = *(const uint4*)&seqstg[(((size_t)(t * 16 + v)) * 4 + mtw * 2 + 1) * 512 + lane * 8];
        float inv = 1.0f / wmax_all[tm];
        const float* wrow = &w_all[(size_t)tm * (B * V * V) + (a_b * V + v) * V];
        float4 wr0 = *(const float4*)(wrow);
        float4 wr1 = *(const float4*)(wrow + 4);
        float4 wr2 = *(const float4*)(wrow + 8);
        float4 wr3 = *(const float4*)(wrow + 12);
        float cprev[4];
#pragma unroll
        for (int r = 0; r < 4; ++r)
            cprev[r] = c[((mtw * 16 + q4 + r) * V + v) * H + col];

        f32x4 acc[4];
        acc[0][0] = bi;  acc[0][1] = bi;  acc[0][2] = bi;  acc[0][3] = bi;
        acc[1][0] = bf_; acc[1][1] = bf_; acc[1][2] = bf_; acc[1][3] = bf_;
        acc[2][0] = bg_; acc[2][1] = bg_; acc[2][2] = bg_; acc[2][3] = bg_;
        acc[3][0] = bo;  acc[3][1] = bo;  acc[3][2] = bo;  acc[3][3] = bo;
        {   // x-part MFMAs (ks=0,1) are wh-independent
            bf16x8 a0f = mk_bf16x8q(s0);
            bf16x8 a1f = mk_bf16x8q(s1);
#pragma unroll
            for (int g = 0; g < 4; ++g)
                acc[g] = mfma16(a0f, *(const bf16x8*)&Wlds[(0 * 8 + (g * 2 + hh)) * 512 + lane * 8], acc[g]);
#pragma unroll
            for (int g = 0; g < 4; ++g)
                acc[g] = mfma16(a1f, *(const bf16x8*)&Wlds[(1 * 8 + (g * 2 + hh)) * 512 + lane * 8], acc[g]);
        }

        // ---- hop 1: h(t) hk-slice ready (16 producers B(*,hk,t-1)) --------
        if (t > 0) {
            if (tid < 16) {
                while (ld_agent_u32(bpoll) < (unsigned)t) __builtin_amdgcn_s_sleep(1);
            }
            __syncthreads();
        }

        // ---- phase A: wh[:, v, hk-slice], one (b, 4-col) chunk per thread -
        {
            const ull* hb = (const ull*)&hin[(a_b * V) * H + hk * 32 + a_cq * 4];
            float a0 = 0.f, a1 = 0.f, a2 = 0.f, a3 = 0.f;
            const float wj[16] = {wr0.x, wr0.y, wr0.z, wr0.w, wr1.x, wr1.y, wr1.z, wr1.w,
                                  wr2.x, wr2.y, wr2.z, wr2.w, wr3.x, wr3.y, wr3.z, wr3.w};
#pragma unroll
            for (int j = 0; j < 16; ++j) {
                ull lo = ld_agent(hb + (size_t)j * (H / 2));
                ull hi = ld_agent(hb + (size_t)j * (H / 2) + 1);
                union { ull u; float f[2]; } u0, u1;
                u0.u = lo; u1.u = hi;
                a0 = fmaf(wj[j], u0.f[0], a0);
                a1 = fmaf(wj[j], u0.f[1], a1);
                a2 = fmaf(wj[j], u1.f[0], a2);
                a3 = fmaf(wj[j], u1.f[1], a3);
            }
            union { u16 u[4]; ull q; } pk;
            pk.u[0] = f2bf(a0 * inv); pk.u[1] = f2bf(a1 * inv);
            pk.u[2] = f2bf(a2 * inv); pk.u[3] = f2bf(a3 * inv);
            st_agent((ull*)&whstg[par * WHP + wh_idx], pk.q);
        }
        __syncthreads();  // per-wave drain of wh stores (pre-barrier waitcnt)
        if (tid == 0) st_agent_u32(aslot, (unsigned)(t + 1));

        // ---- hop 2: wh[:, v, :] ready (16 producers A(v,*,t)) -------------
        if (tid < 16) {
            while (ld_agent_u32(apoll) < (unsigned)(t + 1)) __builtin_amdgcn_s_sleep(1);
        }
        __syncthreads();

        // ---- phase B: h-part MFMAs (ks=2..17) -----------------------------
        bf16x8 afr[16];
#pragma unroll
        for (int ksw = 0; ksw < 16; ++ksw) {
            const ull* src = (const ull*)&whstg[par * WHP + (((v * 2 + mtw) * 16 + ksw) * 64 + lane) * 8];
            ull lo = ld_agent(src), hi = ld_agent(src + 1);
            afr[ksw] = mk_bf16x8(lo, hi);
        }
#pragma unroll
        for (int ks = 0; ks < 16; ++ks) {
#pragma unroll
            for (int g = 0; g < 4; ++g) {
                bf16x8 wfr = *(const bf16x8*)&Wlds[((ks + 2) * 8 + (g * 2 + hh)) * 512 + lane * 8];
                acc[g] = mfma16(afr[ks], wfr, acc[g]);
            }
        }

        // ---- epilogue, signal-early: h stores only, then flag -------------
        float cnv[4], hnv[4];
#pragma unroll
        for (int r = 0; r < 4; ++r) {
            float gi = acc[0][r];
            float gf = acc[1][r];
            float gg = acc[2][r];
            float go = acc[3][r];
            cnv[r] = sigmoidf_(gf) * cprev[r] + sigmoidf_(gi) * tanhf(gg);
            hnv[r] = sigmoidf_(go) * tanhf(cnv[r]);
            int b = mtw * 16 + q4 + r;
            st_agent_f(&hout[(b * V + v) * H + col], hnv[r]);
        }
        if (t < T) {
            __syncthreads();  // per-wave drain of h stores
            if (tid == 0) st_agent_u32(bslot, (unsigned)(t + 1));
        }

        // ---- post-signal: enc + c (off the critical path) -----------------
        // enc is agent-scope now: fused attn reads it cross-block in-kernel.
#pragma unroll
        for (int r = 0; r < 4; ++r) {
            int b = mtw * 16 + q4 + r;
            c[(b * V + v) * H + col] = cnv[r];
            if (t < T) st_agent_u16(&enc[((size_t)(b * V + v) * T + t) * H + col], f2bf(hnv[r]));
        }
    }

    // =========================== fused tail ================================
    // full-grid rdone barrier: all enc + final-h stores visible; w_all dead.
    __syncthreads();  // drains this block's last enc/c/h stores
    if (tid == 0) st_agent_u32(bar + (512 + bid) * 16, 1u);
    {
        const unsigned* rs = bar + (512 + tid) * 16;
        while (ld_agent_u32(rs) < 1u) __builtin_amdgcn_s_sleep(1);
    }
    __syncthreads();

    // ---- attn: 2 units per block: (b = bid>>4 + u*16, v = bid&15) ---------
    for (int u = 0; u < 2; ++u) {
        int ab = (bid >> 4) + u * 16;
        int av = bid & 15;
        const u16* encb = enc + ((size_t)(ab * V + av) * T) * H;
        {   // hs <- final h (agent): 2 floats per thread
            ull x = ld_agent((const ull*)(h0buf + (ab * V + av) * H) + tid);
            union { ull u; float f[2]; } q; q.u = x;
            hs[tid * 2] = q.f[0]; hs[tid * 2 + 1] = q.f[1];
        }
        __syncthreads();
        // scores: wave handles tt stride-4; lane owns cols [lane*8, lane*8+8)
        for (int tt = wvi; tt < T; tt += 4) {
            const ull* ep = (const ull*)(encb + tt * H + lane * 8);
            ull lo = ld_agent(ep), hi = ld_agent(ep + 1);
            union { ull u; u16 s[4]; } x0, x1; x0.u = lo; x1.u = hi;
            const float* hq = &hs[lane * 8];
            float p = bf2f(x0.s[0]) * hq[0] + bf2f(x0.s[1]) * hq[1]
                    + bf2f(x0.s[2]) * hq[2] + bf2f(x0.s[3]) * hq[3]
                    + bf2f(x1.s[0]) * hq[4] + bf2f(x1.s[1]) * hq[5]
                    + bf2f(x1.s[2]) * hq[6] + bf2f(x1.s[3]) * hq[7];
            for (int off = 32; off; off >>= 1) p += __shfl_down(p, off, 64);
            if (lane == 0) scal[tt] = p;
        }
        __syncthreads();
        if (tid < 64) {
            float m_t = mask[(ab * V + av) * T + tid];
            float s = scal[tid] * m_t;
            float mx = s;
            for (int off = 32; off; off >>= 1) mx = fmaxf(mx, __shfl_xor(mx, off, 64));
            float e = __expf(s - mx);
            float sum = e;
            for (int off = 32; off; off >>= 1) sum += __shfl_xor(sum, off, 64);
            scal[T + tid] = e / sum;
        }
        __syncthreads();
        // ctx: threads 0..127, group g = tid -> cols [4g, 4g+4)
        if (tid < 128) {
            float a0 = 0.f, a1 = 0.f, a2 = 0.f, a3 = 0.f;
            for (int tt = 0; tt < T; ++tt) {
                ull x = ld_agent((const ull*)(encb + tt * H + tid * 4));
                union { ull u; u16 s[4]; } q; q.u = x;
                float al = scal[T + tt];
                a0 = fmaf(al, bf2f(q.s[0]), a0);
                a1 = fmaf(al, bf2f(q.s[1]), a1);
                a2 = fmaf(al, bf2f(q.s[2]), a2);
                a3 = fmaf(al, bf2f(q.s[3]), a3);
            }
            float* cp = ctx + (ab * V + av) * H + tid * 4;
            union { float f[2]; ull u; } q0, q1;
            q0.f[0] = a0; q0.f[1] = a1; q1.f[0] = a2; q1.f[1] = a3;
            st_agent((ull*)cp, q0.u);
            st_agent((ull*)cp + 1, q1.u);
        }
        __syncthreads();
    }
    __syncthreads();  // drain ctx stores (all waves)
    if (tid == 0) st_agent_u32(bar + (768 + bid) * 16, 1u);

    // ---- soft: block -> (v = bid&15, h0 = (bid>>4)*32) --------------------
    {
        int sv = bid & 15;
        int h0 = (bid >> 4) * 32;
        if (tid < 16) {  // wait ctx of all 32 b for vessel sv (16 attn blocks)
            const unsigned* cs = bar + (768 + tid * 16 + sv) * 16;
            while (ld_agent_u32(cs) < 1u) __builtin_amdgcn_s_sleep(1);
        }
        __syncthreads();

        int cg = tid & 31, rg = tid >> 5;
        float* sAf = &sA[0][0];
        float* sWf = &sW2[0][0];
        float accs[4] = {0.f, 0.f, 0.f, 0.f};
        int arow = tid >> 3, akq = tid & 7;
        float4 areg, wreg;
        {
            int k = akq * 4;
            const float* src = (arow < 16) ? ctx : h0buf;
            int bsrc = 2 * (arow & 15) + (k >= H ? 1 : 0);
            const float* sp = &src[(bsrc * V + sv) * H + (k & (H - 1))];
            ull l0 = ld_agent((const ull*)sp), l1 = ld_agent((const ull*)sp + 1);
            union { ull u[2]; float4 f; } q; q.u[0] = l0; q.u[1] = l1;
            areg = q.f;
            wreg = *(const float4*)&soft_W[(sv * H + h0 + arow) * (2 * H) + k];
        }
        for (int kc = 0; kc < 2 * H; kc += 32) {
            __syncthreads();
            *(float4*)&sAf[arow * 36 + akq * 4] = areg;
            *(float4*)&sWf[arow * 36 + akq * 4] = wreg;
            __syncthreads();
            if (kc + 32 < 2 * H) {
                int k = kc + 32 + akq * 4;
                const float* src = (arow < 16) ? ctx : h0buf;
                int bsrc = 2 * (arow & 15) + (k >= H ? 1 : 0);
                const float* sp = &src[(bsrc * V + sv) * H + (k & (H - 1))];
                ull l0 = ld_agent((const ull*)sp), l1 = ld_agent((const ull*)sp + 1);
                union { ull u[2]; float4 f; } q; q.u[0] = l0; q.u[1] = l1;
                areg = q.f;
                wreg = *(const float4*)&soft_W[(sv * H + h0 + arow) * (2 * H) + kc + 32 + akq * 4];
            }
#pragma unroll
            for (int k4 = 0; k4 < 8; ++k4) {
                float4 wv = *(const float4*)&sWf[cg * 36 + k4 * 4];
                float4 a0 = *(const float4*)&sAf[(rg * 4 + 0) * 36 + k4 * 4];
                float4 a1 = *(const float4*)&sAf[(rg * 4 + 1) * 36 + k4 * 4];
                float4 a2 = *(const float4*)&sAf[(rg * 4 + 2) * 36 + k4 * 4];
                float4 a3 = *(const float4*)&sAf[(rg * 4 + 3) * 36 + k4 * 4];
                accs[0] += a0.x * wv.x + a0.y * wv.y + a0.z * wv.z + a0.w * wv.w;
                accs[1] += a1.x * wv.x + a1.y * wv.y + a1.z * wv.z + a1.w * wv.w;
                accs[2] += a2.x * wv.x + a2.y * wv.y + a2.z * wv.z + a2.w * wv.w;
                accs[3] += a3.x * wv.x + a3.y * wv.y + a3.z * wv.z + a3.w * wv.w;
            }
        }
        float bb = soft_b[sv * H + h0 + cg];
#pragma unroll
        for (int r = 0; r < 4; ++r) {
            int row = rg * 4 + r;
            st_agent_f(&hsoft[(row * V + sv) * H + h0 + cg], tanhf(accs[r] + bb));
        }
    }
    __syncthreads();  // drain hsoft stores
    if (tid == 0) st_agent_u32(bar + (1024 + bid) * 16, 1u);

    // ---- out: waves 0,1 -> units (b = bid>>4 + wvi*16, v = bid&15) --------
    {
        int ov = bid & 15;
        if (tid < 16) {  // wait hsoft of all 16 h0 slices for vessel ov
            const unsigned* ss = bar + (1024 + tid * 16 + ov) * 16;
            while (ld_agent_u32(ss) < 1u) __builtin_amdgcn_s_sleep(1);
        }
        __syncthreads();
        if (wvi < 2) {
            int ob = (bid >> 4) + wvi * 16;
            const float* hbp = hsoft + (ob * V + ov) * H + lane * 8;
            ull q0 = ld_agent((const ull*)hbp);
            ull q1 = ld_agent((const ull*)hbp + 1);
            ull q2 = ld_agent((const ull*)hbp + 2);
            ull q3 = ld_agent((const ull*)hbp + 3);
            union { ull u[4]; float f[8]; } hv;
            hv.u[0] = q0; hv.u[1] = q1; hv.u[2] = q2; hv.u[3] = q3;
            float p[4] = {0.f, 0.f, 0.f, 0.f};
#pragma unroll
            for (int o = 0; o < 4; ++o) {
                const float* wp = &out_W[o * H + lane * 8];
#pragma unroll
                for (int j = 0; j < 8; ++j) p[o] += hv.f[j] * wp[j];
            }
#pragma unroll
            for (int o = 0; o < 4; ++o) {
                float s = p[o];
                for (int off = 32; off; off >>= 1) s += __shfl_down(s, off, 64);
                if (lane == 0) {
                    float val = s + out_b[o];
                    out[(ob * V + ov) * 4 + o] = val > 0.0f ? val : 0.0f;
                }
            }
        }
    }
}

// ---------------------------------------------------------------------------
extern "C" void kernel_launch(void* const* d_in, const int* in_sizes, int n_in,
                              void* d_out, int out_size, void* d_ws, size_t ws_size,
                              hipStream_t stream) {
    const float* seq = (const float*)d_in[0];
    const float* dist = (const float*)d_in[1];
    const int* rb = (const int*)d_in[2];
    const int* cog = (const int*)d_in[3];
    const float* mask = (const float*)d_in[4];
    const float* maxval = (const float*)d_in[5];
    const float* minval = (const float*)d_in[6];
    const float* W_ih = (const float*)d_in[7];
    const float* W_hh = (const float*)d_in[8];
    const float* b_ih = (const float*)d_in[9];
    const float* b_hh = (const float*)d_in[10];
    const float* domain = (const float*)d_in[11];
    const float* soft_W = (const float*)d_in[12];
    const float* soft_b = (const float*)d_in[13];
    const float* out_W = (const float*)d_in[14];
    const float* out_b = (const float*)d_in[15];

    float* ws = (float*)d_ws;
    float* h0buf = ws + OFF_H0;
    float* h1buf = ws + OFF_H1;
    float* c = ws + OFF_C;
    unsigned* bar = (unsigned*)(ws + OFF_CNT);
    float* w_all = ws + OFF_WALL;
    float* ctx = ws + OFF_CTX;      // alias (w_all dead after full rdone barrier)
    float* hsoft = ws + OFF_HSOFT;  // alias
    float* wmax_all = ws + OFF_WMAX;
    u16* whstg = (u16*)(ws + OFF_WHSTG);
    u16* seqstg = (u16*)(ws + OFF_SEQSTG);
    u16* Wstg = (u16*)(ws + OFF_WSTG);
    u16* enc = (u16*)(ws + OFF_ENC);

    // allow >64 KB dynamic LDS for k_main (idempotent; capture-safe host call)
    (void)hipFuncSetAttribute((const void*)k_main,
                              hipFuncAttributeMaxDynamicSharedMemorySize, WLDS_BYTES);

    // fused preprocessing: zero [0,819200) + hw_all + wconv + seqstg
    k_prep<<<NZB + NHW + NWC + NSS, 256, 0, stream>>>(
        ws, dist, rb, cog, mask, domain, w_all, wmax_all,
        W_ih, W_hh, Wstg, seq, maxval, minval, seqstg);

    // recurrence + attn + soft + out, one persistent launch
    k_main<<<256, 256, WLDS_BYTES, stream>>>(seqstg, Wstg, w_all, wmax_all,
                                             b_ih, b_hh, h0buf, h1buf, c, enc,
                                             whstg, bar, mask, soft_W, soft_b,
                                             out_W, out_b, ctx, hsoft,
                                             (float*)d_out);
}

// Round 7
// 709.954 us; speedup vs baseline: 1.2065x; 1.2065x over previous
//
#include <hip/hip_runtime.h>
#include <math.h>

#define B 32
#define V 16
#define T 64
#define F 64
#define H 512
#define NB 36
#define G4H 2048

typedef unsigned short u16;
typedef unsigned long long ull;
typedef __attribute__((ext_vector_type(8))) short bf16x8;
typedef __attribute__((ext_vector_type(4))) float f32x4;

// workspace offsets (float units)
#define OFF_H0     0           // 262144
#define OFF_H1     262144      // 262144
#define OFF_C      524288      // 262144
#define OFF_CNT    786432      // 32768 words: flag slots, 64B padded
#define OFF_WALL   819200      // 524288 fp32 w_all; ctx/hsoft alias (dead after recur)
#define OFF_CTX    819200      // 262144 (alias; written only in k_tail)
#define OFF_HSOFT  1081344     // 262144 (alias; written only in k_tail)
#define OFF_WMAX   1343488     // 64
#define OFF_WHSTG  1343552     // 262144 fl = 2 parities x 262144 u16 (wh, A-frag bf16)
#define OFF_SEQSTG 1605696     // 1064960 fl = 2129920 u16 (seq all t + denorm t=64, A-frag)
#define OFF_WSTG   2670656     // 9437184 fl (weights, B-frag bf16)
#define OFF_ENC    12107840    // 8388608 fl = 16777216 u16 (enc bf16)
// total 20,496,448 fl = 82.0 MB

#define WHP 262144   // u16 per whstg parity
#define WLDS_BYTES 147456  // 144 KB per-block weight slice (dynamic LDS)

__device__ __forceinline__ float sigmoidf_(float x) { return 1.0f / (1.0f + __expf(-x)); }

__device__ __forceinline__ u16 f2bf(float f) {  // RNE fp32->bf16
    union { float f; unsigned u; } x; x.f = f;
    unsigned r = x.u + 0x7FFF + ((x.u >> 16) & 1);
    return (u16)(r >> 16);
}
__device__ __forceinline__ float bf2f(u16 u) {
    union { unsigned i; float f; } x; x.i = ((unsigned)u) << 16;
    return x.f;
}
__device__ __forceinline__ f32x4 mfma16(bf16x8 a, bf16x8 b, f32x4 c) {
    return __builtin_amdgcn_mfma_f32_16x16x32_bf16(a, b, c, 0, 0, 0);
}
__device__ __forceinline__ bf16x8 mk_bf16x8(ull lo, ull hi) {
    union { ull u[2]; bf16x8 v; } x; x.u[0] = lo; x.u[1] = hi; return x.v;
}
__device__ __forceinline__ bf16x8 mk_bf16x8q(uint4 q) {
    union { uint4 q; bf16x8 v; } x; x.q = q; return x.v;
}

// device-scope coherent accesses (serviced at coherence point; no fences)
__device__ __forceinline__ ull ld_agent(const ull* p) {
    return __hip_atomic_load((ull*)p, __ATOMIC_RELAXED, __HIP_MEMORY_SCOPE_AGENT);
}
__device__ __forceinline__ void st_agent(ull* p, ull x) {
    __hip_atomic_store(p, x, __ATOMIC_RELAXED, __HIP_MEMORY_SCOPE_AGENT);
}
__device__ __forceinline__ void st_agent_f(float* p, float x) {
    __hip_atomic_store(p, x, __ATOMIC_RELAXED, __HIP_MEMORY_SCOPE_AGENT);
}
__device__ __forceinline__ void st_agent_u32(unsigned* p, unsigned x) {
    __hip_atomic_store(p, x, __ATOMIC_RELAXED, __HIP_MEMORY_SCOPE_AGENT);
}
__device__ __forceinline__ unsigned ld_agent_u32(const unsigned* p) {
    return __hip_atomic_load((unsigned*)p, __ATOMIC_RELAXED, __HIP_MEMORY_SCOPE_AGENT);
}

// ---------------------------------------------------------------------------
// Fused one-time preprocessing: [0,3200)=zero, [3200,3264)=hw_all,
// [3264,3520)=wconv (coalesced LDS-transpose), [3520,4560)=seqstg.
#define NZB 3200
#define NHW 64
#define NWC 256
#define NSS 1040
__global__ __launch_bounds__(256) void k_prep(
    float* __restrict__ ws,
    const float* __restrict__ dist, const int* __restrict__ rb,
    const int* __restrict__ cog, const float* __restrict__ mask,
    const float* __restrict__ domain, float* __restrict__ w_all,
    float* __restrict__ wmax_all,
    const float* __restrict__ W_ih, const float* __restrict__ W_hh,
    u16* __restrict__ Wstg,
    const float* __restrict__ seq, const float* __restrict__ maxval,
    const float* __restrict__ minval, u16* __restrict__ seqstg) {
    __shared__ float red[256];
    __shared__ float tile[128 * 36];   // wconv staging, +36 pad (18.4 KB)
    int bid = blockIdx.x;
    int tid = threadIdx.x;

    if (bid < NZB) {
        // ---- zero h0,h1,c + flag slots: [0, 819200)
        ws[bid * 256 + tid] = 0.0f;
        return;
    }
    if (bid < NZB + NHW) {
        // ---- hardwired weights for all t
        int t = bid - NZB;
        float lmax = 0.0f;
        for (int idx = tid; idx < B * V * V; idx += 256) {
            int b = idx >> 8;
            int rem = idx & 255;
            int i = rem >> 4, j = rem & 15;
            int base = ((b * V + i) * T + t) * V + j;
            float val = domain[cog[base] * NB + rb[base]] - dist[base];
            val = val > 0.0f ? val : 0.0f;
            val *= mask[(b * V + i) * T + t] * mask[(b * V + j) * T + t];
            w_all[t * (B * V * V) + idx] = val;
            lmax = fmaxf(lmax, val);
        }
        red[tid] = lmax;
        __syncthreads();
        for (int s = 128; s > 0; s >>= 1) {
            if (tid < s) red[tid] = fmaxf(red[tid], red[tid + s]);
            __syncthreads();
        }
        if (tid == 0) wmax_all[t] = red[0];
        return;
    }
    if (bid < NZB + NHW + NWC) {
        // ---- W_ih||W_hh -> bf16 B-fragment layout, COALESCED via LDS tile.
        // Block (v,hk).  Per ks: stage rows {g*512+hk*32+[0,32), g=0..3} x
        // k-chunk [ks*32, ks*32+32) as tile[128][36] (2 lanes x 64B per row,
        // contiguous), then emit fragments with coalesced 16B/lane writes.
        int idx = bid - (NZB + NHW);
        int v = idx >> 4, hk = idx & 15;
        int lr = tid >> 1, half = tid & 1;       // load map: row, 16-float half
        int lg = lr >> 5, rloc = lr & 31;
        int srcrow = v * G4H + lg * 512 + hk * 32 + rloc;
        for (int ks = 0; ks < 18; ++ks) {
            const float* srcp = (ks < 2)
                ? &W_ih[srcrow * F + ks * 32 + half * 16]
                : &W_hh[srcrow * H + (ks * 32 - 64) + half * 16];
            float4 x0 = *(const float4*)srcp;
            float4 x1 = *(const float4*)(srcp + 4);
            float4 x2 = *(const float4*)(srcp + 8);
            float4 x3 = *(const float4*)(srcp + 12);
            __syncthreads();  // WAR: previous iteration's LDS reads complete
            float* dst = &tile[lr * 36 + half * 16];
            *(float4*)(dst + 0) = x0;
            *(float4*)(dst + 4) = x1;
            *(float4*)(dst + 8) = x2;
            *(float4*)(dst + 12) = x3;
            __syncthreads();
#pragma unroll
            for (int s = 0; s < 2; ++s) {
                int slot = tid + s * 256;
                int nt = slot >> 6, lane = slot & 63;
                int g = nt >> 1, hh = nt & 1;
                int ldsrow = g * 32 + hh * 16 + (lane & 15);
                int kloc = (lane >> 4) << 3;
                float4 y0 = *(const float4*)&tile[ldsrow * 36 + kloc];
                float4 y1 = *(const float4*)&tile[ldsrow * 36 + kloc + 4];
                union { u16 u[8]; uint4 q; } pk;
                pk.u[0] = f2bf(y0.x); pk.u[1] = f2bf(y0.y);
                pk.u[2] = f2bf(y0.z); pk.u[3] = f2bf(y0.w);
                pk.u[4] = f2bf(y1.x); pk.u[5] = f2bf(y1.y);
                pk.u[6] = f2bf(y1.z); pk.u[7] = f2bf(y1.w);
                *(uint4*)&Wstg[(size_t)((((v * 16 + hk) * 18 + ks) * 8 + nt) * 64 + lane) * 8] = pk.q;
            }
        }
        return;
    }
    {
        // ---- pack seq (t=64 = denormalized last input) into A-frag bf16:
        // seqstg[t][v][mt2][ks2][lane64][8]
        int idx = bid - (NZB + NHW + NWC);
        int v = idx / 65, t = idx % 65;
        int mt = tid >> 7, ks = (tid >> 6) & 1, lane = tid & 63;
        int b = mt * 16 + (lane & 15);
        int f = ks * 32 + ((lane >> 4) << 3);
        union { u16 u[8]; uint4 q; } pk;
        if (t < T) {
            const float* sp = &seq[((b * V + v) * T + t) * F + f];
            float4 x0 = *(const float4*)sp, x1 = *(const float4*)(sp + 4);
            pk.u[0] = f2bf(x0.x); pk.u[1] = f2bf(x0.y); pk.u[2] = f2bf(x0.z); pk.u[3] = f2bf(x0.w);
            pk.u[4] = f2bf(x1.x); pk.u[5] = f2bf(x1.y); pk.u[6] = f2bf(x1.z); pk.u[7] = f2bf(x1.w);
        } else {
            const float* sp = &seq[((b * V + v) * T + (T - 1)) * F + f];
            float4 x0 = *(const float4*)sp, x1 = *(const float4*)(sp + 4);
            float4 mx0 = *(const float4*)&maxval[b * F + f], mx1 = *(const float4*)&maxval[b * F + f + 4];
            float4 mn0 = *(const float4*)&minval[b * F + f], mn1 = *(const float4*)&minval[b * F + f + 4];
            pk.u[0] = f2bf(x0.x * (mx0.x - mn0.x) + mn0.x);
            pk.u[1] = f2bf(x0.y * (mx0.y - mn0.y) + mn0.y);
            pk.u[2] = f2bf(x0.z * (mx0.z - mn0.z) + mn0.z);
            pk.u[3] = f2bf(x0.w * (mx0.w - mn0.w) + mn0.w);
            pk.u[4] = f2bf(x1.x * (mx1.x - mn1.x) + mn1.x);
            pk.u[5] = f2bf(x1.y * (mx1.y - mn1.y) + mn1.y);
            pk.u[6] = f2bf(x1.z * (mx1.z - mn1.z) + mn1.z);
            pk.u[7] = f2bf(x1.w * (mx1.w - mn1.w) + mn1.w);
        }
        *(uint4*)&seqstg[(((size_t)(t * 16 + v)) * 4 + mt * 2 + ks) * 512 + lane * 8] = pk.q;
    }
}

// ---------------------------------------------------------------------------
// Persistent recurrence (R12 structure verbatim, empirically 498 us).
// enc/h published by PLAIN/L2 stores; kernel boundary flushes for k_tail.
__global__ __launch_bounds__(256) void k_recur(
    const u16* __restrict__ seqstg, const u16* __restrict__ Wstg,
    const float* __restrict__ w_all, const float* __restrict__ wmax_all,
    const float* __restrict__ b_ih, const float* __restrict__ b_hh,
    float* __restrict__ h0buf, float* __restrict__ h1buf,
    float* __restrict__ c, u16* __restrict__ enc, u16* __restrict__ whstg,
    unsigned* __restrict__ bar) {
    extern __shared__ u16 Wlds[];          // 144 KB weight slice

    int bid = blockIdx.x;
    int v = bid & 15, hk = bid >> 4;
    int tid = threadIdx.x;

    // ---- one-time: pin weight slice in LDS
    {
        const uint4* wsrc = (const uint4*)(Wstg + (size_t)((v * 16 + hk) * 18) * 4096);
        uint4* wdst = (uint4*)Wlds;
        for (int i = tid; i < 9216; i += 256) wdst[i] = wsrc[i];
    }

    int lane = tid & 63, wvi = tid >> 6;
    int mtw = wvi & 1, hh = wvi >> 1;
    int col = hk * 32 + hh * 16 + (lane & 15);
    int q4 = (lane >> 4) << 2;
    float bi = b_ih[v * G4H + col] + b_hh[v * G4H + col];
    float bf_ = b_ih[v * G4H + H + col] + b_hh[v * G4H + H + col];
    float bg_ = b_ih[v * G4H + 2 * H + col] + b_hh[v * G4H + 2 * H + col];
    float bo = b_ih[v * G4H + 3 * H + col] + b_hh[v * G4H + 3 * H + col];

    // flag slots: 64B padded.  aflag slot (v*16+hk); bflag slot 256+(hk*16+v)
    unsigned* aslot = bar + (v * 16 + hk) * 16;
    unsigned* bslot = bar + (256 + hk * 16 + v) * 16;
    unsigned* apoll = bar + (v * 16 + (tid & 15)) * 16;          // B-wait family v
    unsigned* bpoll = bar + (256 + hk * 16 + (tid & 15)) * 16;   // A-wait family hk

    // phase-A thread map: thread = (b = tid>>3, colq = tid&7)
    int a_b = tid >> 3;
    int a_cq = tid & 7;
    const int wh_idx = ((((v * 2 + (a_b >> 4)) * 16 + hk) * 64 +
                         (((a_cq >> 1) << 4) + (a_b & 15))) * 8 + (a_cq & 1) * 4);

    __syncthreads();  // W-LDS fill complete

    for (int t = 0; t <= T; ++t) {
        int par = t & 1;
        int tm = t < T ? t : (T - 1);
        const float* hin = (t & 1) ? h0buf : h1buf;
        float* hout = (t & 1) ? h1buf : h0buf;

        // ---- pre-wait independent work ------------------------------------
        uint4 s0 = *(const uint4*)&seqstg[(((size_t)(t * 16 + v)) * 4 + mtw * 2 + 0) * 512 + lane * 8];
        uint4 s1 = *(const uint4*)&seqstg[(((size_t)(t * 16 + v)) * 4 + mtw * 2 + 1) * 512 + lane * 8];
        float inv = 1.0f / wmax_all[tm];
        const float* wrow = &w_all[(size_t)tm * (B * V * V) + (a_b * V + v) * V];
        float4 wr0 = *(const float4*)(wrow);
        float4 wr1 = *(const float4*)(wrow + 4);
        float4 wr2 = *(const float4*)(wrow + 8);
        float4 wr3 = *(const float4*)(wrow + 12);
        float cprev[4];
#pragma unroll
        for (int r = 0; r < 4; ++r)
            cprev[r] = c[((mtw * 16 + q4 + r) * V + v) * H + col];

        f32x4 acc[4];
        acc[0][0] = bi;  acc[0][1] = bi;  acc[0][2] = bi;  acc[0][3] = bi;
        acc[1][0] = bf_; acc[1][1] = bf_; acc[1][2] = bf_; acc[1][3] = bf_;
        acc[2][0] = bg_; acc[2][1] = bg_; acc[2][2] = bg_; acc[2][3] = bg_;
        acc[3][0] = bo;  acc[3][1] = bo;  acc[3][2] = bo;  acc[3][3] = bo;
        {   // x-part MFMAs (ks=0,1) are wh-independent
            bf16x8 a0f = mk_bf16x8q(s0);
            bf16x8 a1f = mk_bf16x8q(s1);
#pragma unroll
            for (int g = 0; g < 4; ++g)
                acc[g] = mfma16(a0f, *(const bf16x8*)&Wlds[(0 * 8 + (g * 2 + hh)) * 512 + lane * 8], acc[g]);
#pragma unroll
            for (int g = 0; g < 4; ++g)
                acc[g] = mfma16(a1f, *(const bf16x8*)&Wlds[(1 * 8 + (g * 2 + hh)) * 512 + lane * 8], acc[g]);
        }

        // ---- hop 1: h(t) hk-slice ready (16 producers B(*,hk,t-1)) --------
        if (t > 0) {
            if (tid < 16) {
                while (ld_agent_u32(bpoll) < (unsigned)t) __builtin_amdgcn_s_sleep(1);
            }
            __syncthreads();
        }

        // ---- phase A: wh[:, v, hk-slice], one (b, 4-col) chunk per thread -
        {
            const ull* hb = (const ull*)&hin[(a_b * V) * H + hk * 32 + a_cq * 4];
            float a0 = 0.f, a1 = 0.f, a2 = 0.f, a3 = 0.f;
            const float wj[16] = {wr0.x, wr0.y, wr0.z, wr0.w, wr1.x, wr1.y, wr1.z, wr1.w,
                                  wr2.x, wr2.y, wr2.z, wr2.w, wr3.x, wr3.y, wr3.z, wr3.w};
#pragma unroll
            for (int j = 0; j < 16; ++j) {
                ull lo = ld_agent(hb + (size_t)j * (H / 2));
                ull hi = ld_agent(hb + (size_t)j * (H / 2) + 1);
                union { ull u; float f[2]; } u0, u1;
                u0.u = lo; u1.u = hi;
                a0 = fmaf(wj[j], u0.f[0], a0);
                a1 = fmaf(wj[j], u0.f[1], a1);
                a2 = fmaf(wj[j], u1.f[0], a2);
                a3 = fmaf(wj[j], u1.f[1], a3);
            }
            union { u16 u[4]; ull q; } pk;
            pk.u[0] = f2bf(a0 * inv); pk.u[1] = f2bf(a1 * inv);
            pk.u[2] = f2bf(a2 * inv); pk.u[3] = f2bf(a3 * inv);
            st_agent((ull*)&whstg[par * WHP + wh_idx], pk.q);
        }
        __syncthreads();  // per-wave drain of wh stores (pre-barrier waitcnt)
        if (tid == 0) st_agent_u32(aslot, (unsigned)(t + 1));

        // ---- hop 2: wh[:, v, :] ready (16 producers A(v,*,t)) -------------
        if (tid < 16) {
            while (ld_agent_u32(apoll) < (unsigned)(t + 1)) __builtin_amdgcn_s_sleep(1);
        }
        __syncthreads();

        // ---- phase B: h-part MFMAs (ks=2..17) -----------------------------
        bf16x8 afr[16];
#pragma unroll
        for (int ksw = 0; ksw < 16; ++ksw) {
            const ull* src = (const ull*)&whstg[par * WHP + (((v * 2 + mtw) * 16 + ksw) * 64 + lane) * 8];
            ull lo = ld_agent(src), hi = ld_agent(src + 1);
            afr[ksw] = mk_bf16x8(lo, hi);
        }
#pragma unroll
        for (int ks = 0; ks < 16; ++ks) {
#pragma unroll
            for (int g = 0; g < 4; ++g) {
                bf16x8 wfr = *(const bf16x8*)&Wlds[((ks + 2) * 8 + (g * 2 + hh)) * 512 + lane * 8];
                acc[g] = mfma16(afr[ks], wfr, acc[g]);
            }
        }

        // ---- epilogue, signal-early: h stores only, then flag -------------
        float cnv[4], hnv[4];
#pragma unroll
        for (int r = 0; r < 4; ++r) {
            float gi = acc[0][r];
            float gf = acc[1][r];
            float gg = acc[2][r];
            float go = acc[3][r];
            cnv[r] = sigmoidf_(gf) * cprev[r] + sigmoidf_(gi) * tanhf(gg);
            hnv[r] = sigmoidf_(go) * tanhf(cnv[r]);
            int b = mtw * 16 + q4 + r;
            st_agent_f(&hout[(b * V + v) * H + col], hnv[r]);
        }
        if (t < T) {
            __syncthreads();  // per-wave drain of h stores
            if (tid == 0) st_agent_u32(bslot, (unsigned)(t + 1));
        }

        // ---- post-signal: enc + c (off the critical path, PLAIN stores) ---
#pragma unroll
        for (int r = 0; r < 4; ++r) {
            int b = mtw * 16 + q4 + r;
            c[(b * V + v) * H + col] = cnv[r];
            if (t < T) enc[((size_t)(b * V + v) * T + t) * H + col] = f2bf(hnv[r]);
        }
    }
}

// ---------------------------------------------------------------------------
// Fused tail: attn + soft + out in ONE kernel (grid 256).  enc/h arrive via
// the kernel boundary (plain cached loads).  In-kernel cross-block tensors
// (ctx, hsoft) use agent stores/loads + flag hops (slots 768+/1024+, zeroed
// by prep, untouched by k_recur).  ctx/hsoft alias w_all (dead after recur).
__global__ __launch_bounds__(256) void k_tail(
    const u16* __restrict__ enc, const float* __restrict__ hfin,
    const float* __restrict__ mask, const float* __restrict__ soft_W,
    const float* __restrict__ soft_b, const float* __restrict__ out_W,
    const float* __restrict__ out_b, float* __restrict__ ctx,
    float* __restrict__ hsoft, float* __restrict__ out,
    unsigned* __restrict__ bar) {
    __shared__ float hs[H];
    __shared__ float scal[2 * T];
    __shared__ float sA[32][36];
    __shared__ float sW2[32][36];

    int bid = blockIdx.x;
    int tid = threadIdx.x;
    int lane = tid & 63, wvi = tid >> 6;

    // ---- attn: 2 units per block: (b = bid>>4 + u*16, v = bid&15) ---------
    for (int u = 0; u < 2; ++u) {
        int ab = (bid >> 4) + u * 16;
        int av = bid & 15;
        const u16* encb = enc + ((size_t)(ab * V + av) * T) * H;
        {   // hs <- final h (plain)
            float2 q = *(const float2*)(hfin + (ab * V + av) * H + tid * 2);
            hs[tid * 2] = q.x; hs[tid * 2 + 1] = q.y;
        }
        __syncthreads();
        // scores: wave handles tt stride-4; lane owns cols [lane*8, lane*8+8)
        for (int tt = wvi; tt < T; tt += 4) {
            uint4 x = *(const uint4*)(encb + tt * H + lane * 8);
            union { uint4 q; u16 s[8]; } e; e.q = x;
            const float* hq = &hs[lane * 8];
            float p = bf2f(e.s[0]) * hq[0] + bf2f(e.s[1]) * hq[1]
                    + bf2f(e.s[2]) * hq[2] + bf2f(e.s[3]) * hq[3]
                    + bf2f(e.s[4]) * hq[4] + bf2f(e.s[5]) * hq[5]
                    + bf2f(e.s[6]) * hq[6] + bf2f(e.s[7]) * hq[7];
            for (int off = 32; off; off >>= 1) p += __shfl_down(p, off, 64);
            if (lane == 0) scal[tt] = p;
        }
        __syncthreads();
        if (tid < 64) {
            float m_t = mask[(ab * V + av) * T + tid];
            float s = scal[tid] * m_t;
            float mx = s;
            for (int off = 32; off; off >>= 1) mx = fmaxf(mx, __shfl_xor(mx, off, 64));
            float e = __expf(s - mx);
            float sum = e;
            for (int off = 32; off; off >>= 1) sum += __shfl_xor(sum, off, 64);
            scal[T + tid] = e / sum;
        }
        __syncthreads();
        // ctx: threads 0..127, thread g -> cols [4g, 4g+4); agent stores
        if (tid < 128) {
            float a0 = 0.f, a1 = 0.f, a2 = 0.f, a3 = 0.f;
            for (int tt = 0; tt < T; ++tt) {
                ull x = *(const ull*)(encb + tt * H + tid * 4);
                union { ull u; u16 s[4]; } q; q.u = x;
                float al = scal[T + tt];
                a0 = fmaf(al, bf2f(q.s[0]), a0);
                a1 = fmaf(al, bf2f(q.s[1]), a1);
                a2 = fmaf(al, bf2f(q.s[2]), a2);
                a3 = fmaf(al, bf2f(q.s[3]), a3);
            }
            float* cp = ctx + (ab * V + av) * H + tid * 4;
            union { float f[2]; ull u; } q0, q1;
            q0.f[0] = a0; q0.f[1] = a1; q1.f[0] = a2; q1.f[1] = a3;
            st_agent((ull*)cp, q0.u);
            st_agent((ull*)cp + 1, q1.u);
        }
        __syncthreads();
    }
    __syncthreads();  // drain ctx stores (all waves)
    if (tid == 0) st_agent_u32(bar + (768 + bid) * 16, 1u);

    // ---- soft: block -> (v = bid&15, h0 = (bid>>4)*32) --------------------
    {
        int sv = bid & 15;
        int h0 = (bid >> 4) * 32;
        if (tid < 16) {  // wait ctx of all 32 b for vessel sv (16 attn blocks)
            const unsigned* cs = bar + (768 + tid * 16 + sv) * 16;
            while (ld_agent_u32(cs) < 1u) __builtin_amdgcn_s_sleep(1);
        }
        __syncthreads();

        int cg = tid & 31, rg = tid >> 5;
        float* sAf = &sA[0][0];
        float* sWf = &sW2[0][0];
        float accs[4] = {0.f, 0.f, 0.f, 0.f};
        int arow = tid >> 3, akq = tid & 7;
        float4 areg, wreg;
        {
            int k = akq * 4;
            const float* src = (arow < 16) ? ctx : hfin;
            int bsrc = 2 * (arow & 15) + (k >= H ? 1 : 0);
            const float* sp = &src[(bsrc * V + sv) * H + (k & (H - 1))];
            ull l0 = ld_agent((const ull*)sp), l1 = ld_agent((const ull*)sp + 1);
            union { ull u[2]; float4 f; } q; q.u[0] = l0; q.u[1] = l1;
            areg = q.f;
            wreg = *(const float4*)&soft_W[(sv * H + h0 + arow) * (2 * H) + k];
        }
        for (int kc = 0; kc < 2 * H; kc += 32) {
            __syncthreads();
            *(float4*)&sAf[arow * 36 + akq * 4] = areg;
            *(float4*)&sWf[arow * 36 + akq * 4] = wreg;
            __syncthreads();
            if (kc + 32 < 2 * H) {
                int k = kc + 32 + akq * 4;
                const float* src = (arow < 16) ? ctx : hfin;
                int bsrc = 2 * (arow & 15) + (k >= H ? 1 : 0);
                const float* sp = &src[(bsrc * V + sv) * H + (k & (H - 1))];
                ull l0 = ld_agent((const ull*)sp), l1 = ld_agent((const ull*)sp + 1);
                union { ull u[2]; float4 f; } q; q.u[0] = l0; q.u[1] = l1;
                areg = q.f;
                wreg = *(const float4*)&soft_W[(sv * H + h0 + arow) * (2 * H) + kc + 32 + akq * 4];
            }
#pragma unroll
            for (int k4 = 0; k4 < 8; ++k4) {
                float4 wv = *(const float4*)&sWf[cg * 36 + k4 * 4];
                float4 a0 = *(const float4*)&sAf[(rg * 4 + 0) * 36 + k4 * 4];
                float4 a1 = *(const float4*)&sAf[(rg * 4 + 1) * 36 + k4 * 4];
                float4 a2 = *(const float4*)&sAf[(rg * 4 + 2) * 36 + k4 * 4];
                float4 a3 = *(const float4*)&sAf[(rg * 4 + 3) * 36 + k4 * 4];
                accs[0] += a0.x * wv.x + a0.y * wv.y + a0.z * wv.z + a0.w * wv.w;
                accs[1] += a1.x * wv.x + a1.y * wv.y + a1.z * wv.z + a1.w * wv.w;
                accs[2] += a2.x * wv.x + a2.y * wv.y + a2.z * wv.z + a2.w * wv.w;
                accs[3] += a3.x * wv.x + a3.y * wv.y + a3.z * wv.z + a3.w * wv.w;
            }
        }
        float bb = soft_b[sv * H + h0 + cg];
#pragma unroll
        for (int r = 0; r < 4; ++r) {
            int row = rg * 4 + r;
            st_agent_f(&hsoft[(row * V + sv) * H + h0 + cg], tanhf(accs[r] + bb));
        }
    }
    __syncthreads();  // drain hsoft stores
    if (tid == 0) st_agent_u32(bar + (1024 + bid) * 16, 1u);

    // ---- out: waves 0,1 -> units (b = bid>>4 + wvi*16, v = bid&15) --------
    {
        int ov = bid & 15;
        if (tid < 16) {  // wait hsoft of all 16 h0 slices for vessel ov
            const unsigned* ss = bar + (1024 + tid * 16 + ov) * 16;
            while (ld_agent_u32(ss) < 1u) __builtin_amdgcn_s_sleep(1);
        }
        __syncthreads();
        if (wvi < 2) {
            int ob = (bid >> 4) + wvi * 16;
            const float* hbp = hsoft + (ob * V + ov) * H + lane * 8;
            ull q0 = ld_agent((const ull*)hbp);
            ull q1 = ld_agent((const ull*)hbp + 1);
            ull q2 = ld_agent((const ull*)hbp + 2);
            ull q3 = ld_agent((const ull*)hbp + 3);
            union { ull u[4]; float f[8]; } hv;
            hv.u[0] = q0; hv.u[1] = q1; hv.u[2] = q2; hv.u[3] = q3;
            float p[4] = {0.f, 0.f, 0.f, 0.f};
#pragma unroll
            for (int o = 0; o < 4; ++o) {
                const float* wp = &out_W[o * H + lane * 8];
#pragma unroll
                for (int j = 0; j < 8; ++j) p[o] += hv.f[j] * wp[j];
            }
#pragma unroll
            for (int o = 0; o < 4; ++o) {
                float s = p[o];
                for (int off = 32; off; off >>= 1) s += __shfl_down(s, off, 64);
                if (lane == 0) {
                    float val = s + out_b[o];
                    out[(ob * V + ov) * 4 + o] = val > 0.0f ? val : 0.0f;
                }
            }
        }
    }
}

// ---------------------------------------------------------------------------
extern "C" void kernel_launch(void* const* d_in, const int* in_sizes, int n_in,
                              void* d_out, int out_size, void* d_ws, size_t ws_size,
                              hipStream_t stream) {
    const float* seq = (const float*)d_in[0];
    const float* dist = (const float*)d_in[1];
    const int* rb = (const int*)d_in[2];
    const int* cog = (const int*)d_in[3];
    const float* mask = (const float*)d_in[4];
    const float* maxval = (const float*)d_in[5];
    const float* minval = (const float*)d_in[6];
    const float* W_ih = (const float*)d_in[7];
    const float* W_hh = (const float*)d_in[8];
    const float* b_ih = (const float*)d_in[9];
    const float* b_hh = (const float*)d_in[10];
    const float* domain = (const float*)d_in[11];
    const float* soft_W = (const float*)d_in[12];
    const float* soft_b = (const float*)d_in[13];
    const float* out_W = (const float*)d_in[14];
    const float* out_b = (const float*)d_in[15];

    float* ws = (float*)d_ws;
    float* h0buf = ws + OFF_H0;
    float* h1buf = ws + OFF_H1;
    float* c = ws + OFF_C;
    unsigned* bar = (unsigned*)(ws + OFF_CNT);
    float* w_all = ws + OFF_WALL;
    float* ctx = ws + OFF_CTX;      // alias (w_all dead after k_recur)
    float* hsoft = ws + OFF_HSOFT;  // alias
    float* wmax_all = ws + OFF_WMAX;
    u16* whstg = (u16*)(ws + OFF_WHSTG);
    u16* seqstg = (u16*)(ws + OFF_SEQSTG);
    u16* Wstg = (u16*)(ws + OFF_WSTG);
    u16* enc = (u16*)(ws + OFF_ENC);

    // allow >64 KB dynamic LDS for k_recur (idempotent; capture-safe host call)
    (void)hipFuncSetAttribute((const void*)k_recur,
                              hipFuncAttributeMaxDynamicSharedMemorySize, WLDS_BYTES);

    // fused preprocessing: zero [0,819200) + hw_all + wconv + seqstg
    k_prep<<<NZB + NHW + NWC + NSS, 256, 0, stream>>>(
        ws, dist, rb, cog, mask, domain, w_all, wmax_all,
        W_ih, W_hh, Wstg, seq, maxval, minval, seqstg);

    // whole recurrence (64 encoder steps + 1 decoder step) in one launch
    k_recur<<<256, 256, WLDS_BYTES, stream>>>(seqstg, Wstg, w_all, wmax_all,
                                              b_ih, b_hh, h0buf, h1buf, c, enc,
                                              whstg, bar);

    // fused attn + soft + out (final h is in h0buf; t=64 writes buf[0])
    k_tail<<<256, 256, 0, stream>>>(enc, h0buf, mask, soft_W, soft_b,
                                    out_W, out_b, ctx, hsoft,
                                    (float*)d_out, bar);
}

// Round 8
// 693.920 us; speedup vs baseline: 1.2344x; 1.0231x over previous
//
#include <hip/hip_runtime.h>
#include <math.h>

#define B 32
#define V 16
#define T 64
#define F 64
#define H 512
#define NB 36
#define G4H 2048

typedef unsigned short u16;
typedef unsigned long long ull;
typedef __attribute__((ext_vector_type(8))) short bf16x8;
typedef __attribute__((ext_vector_type(4))) float f32x4;

// workspace offsets (float units)
#define OFF_H0     0           // 262144
#define OFF_H1     262144      // 262144
#define OFF_C      524288      // 262144
#define OFF_CNT    786432      // flag slots, 64B padded (20480 words used)
#define OFF_WALL   819200      // 524288 fp32 w_all; ctx/hsoft alias (dead after recur)
#define OFF_CTX    819200      // 262144 (alias; written only in k_tail)
#define OFF_HSOFT  1081344     // 262144 (alias; written only in k_tail)
#define OFF_WMAX   1343488     // 64
#define OFF_WHSTG  1343552     // 262144 fl = 2 parities x 262144 u16 (wh, A-frag bf16)
#define OFF_SEQSTG 1605696     // 1064960 fl = 2129920 u16 (seq all t + denorm t=64, A-frag)
#define OFF_ENC    12107840    // 8388608 fl = 16777216 u16 (enc bf16)
// (Wstg eliminated in R15: weights converted in k_recur prologue)

#define WHP 262144   // u16 per whstg parity
#define WLDS_BYTES 147456  // 144 KB per-block weight slice (dynamic LDS)

__device__ __forceinline__ float sigmoidf_(float x) { return 1.0f / (1.0f + __expf(-x)); }

__device__ __forceinline__ u16 f2bf(float f) {  // RNE fp32->bf16
    union { float f; unsigned u; } x; x.f = f;
    unsigned r = x.u + 0x7FFF + ((x.u >> 16) & 1);
    return (u16)(r >> 16);
}
__device__ __forceinline__ float bf2f(u16 u) {
    union { unsigned i; float f; } x; x.i = ((unsigned)u) << 16;
    return x.f;
}
__device__ __forceinline__ f32x4 mfma16(bf16x8 a, bf16x8 b, f32x4 c) {
    return __builtin_amdgcn_mfma_f32_16x16x32_bf16(a, b, c, 0, 0, 0);
}
__device__ __forceinline__ bf16x8 mk_bf16x8(ull lo, ull hi) {
    union { ull u[2]; bf16x8 v; } x; x.u[0] = lo; x.u[1] = hi; return x.v;
}
__device__ __forceinline__ bf16x8 mk_bf16x8q(uint4 q) {
    union { uint4 q; bf16x8 v; } x; x.q = q; return x.v;
}

// device-scope coherent accesses (serviced at coherence point; no fences)
__device__ __forceinline__ ull ld_agent(const ull* p) {
    return __hip_atomic_load((ull*)p, __ATOMIC_RELAXED, __HIP_MEMORY_SCOPE_AGENT);
}
__device__ __forceinline__ void st_agent(ull* p, ull x) {
    __hip_atomic_store(p, x, __ATOMIC_RELAXED, __HIP_MEMORY_SCOPE_AGENT);
}
__device__ __forceinline__ void st_agent_f(float* p, float x) {
    __hip_atomic_store(p, x, __ATOMIC_RELAXED, __HIP_MEMORY_SCOPE_AGENT);
}
__device__ __forceinline__ void st_agent_u32(unsigned* p, unsigned x) {
    __hip_atomic_store(p, x, __ATOMIC_RELAXED, __HIP_MEMORY_SCOPE_AGENT);
}
__device__ __forceinline__ unsigned ld_agent_u32(const unsigned* p) {
    return __hip_atomic_load((unsigned*)p, __ATOMIC_RELAXED, __HIP_MEMORY_SCOPE_AGENT);
}

// ---------------------------------------------------------------------------
// Prep (R15, shrunk): [0,80)=zero flag slots, [80,144)=hw_all,
// [144,1184)=seqstg.  wconv + h/c zeroing moved into k_recur prologue.
#define NZB 80
#define NHW 64
#define NSS 1040
__global__ __launch_bounds__(256) void k_prep(
    float* __restrict__ ws,
    const float* __restrict__ dist, const int* __restrict__ rb,
    const int* __restrict__ cog, const float* __restrict__ mask,
    const float* __restrict__ domain, float* __restrict__ w_all,
    float* __restrict__ wmax_all,
    const float* __restrict__ seq, const float* __restrict__ maxval,
    const float* __restrict__ minval, u16* __restrict__ seqstg) {
    __shared__ float red[256];
    int bid = blockIdx.x;
    int tid = threadIdx.x;

    if (bid < NZB) {
        // ---- zero flag slots: [OFF_CNT, OFF_CNT + 20480)
        ws[OFF_CNT + bid * 256 + tid] = 0.0f;
        return;
    }
    if (bid < NZB + NHW) {
        // ---- hardwired weights for all t
        int t = bid - NZB;
        float lmax = 0.0f;
        for (int idx = tid; idx < B * V * V; idx += 256) {
            int b = idx >> 8;
            int rem = idx & 255;
            int i = rem >> 4, j = rem & 15;
            int base = ((b * V + i) * T + t) * V + j;
            float val = domain[cog[base] * NB + rb[base]] - dist[base];
            val = val > 0.0f ? val : 0.0f;
            val *= mask[(b * V + i) * T + t] * mask[(b * V + j) * T + t];
            w_all[t * (B * V * V) + idx] = val;
            lmax = fmaxf(lmax, val);
        }
        red[tid] = lmax;
        __syncthreads();
        for (int s = 128; s > 0; s >>= 1) {
            if (tid < s) red[tid] = fmaxf(red[tid], red[tid + s]);
            __syncthreads();
        }
        if (tid == 0) wmax_all[t] = red[0];
        return;
    }
    {
        // ---- pack seq (t=64 = denormalized last input) into A-frag bf16:
        // seqstg[t][v][mt2][ks2][lane64][8]
        int idx = bid - (NZB + NHW);
        int v = idx / 65, t = idx % 65;
        int mt = tid >> 7, ks = (tid >> 6) & 1, lane = tid & 63;
        int b = mt * 16 + (lane & 15);
        int f = ks * 32 + ((lane >> 4) << 3);
        union { u16 u[8]; uint4 q; } pk;
        if (t < T) {
            const float* sp = &seq[((b * V + v) * T + t) * F + f];
            float4 x0 = *(const float4*)sp, x1 = *(const float4*)(sp + 4);
            pk.u[0] = f2bf(x0.x); pk.u[1] = f2bf(x0.y); pk.u[2] = f2bf(x0.z); pk.u[3] = f2bf(x0.w);
            pk.u[4] = f2bf(x1.x); pk.u[5] = f2bf(x1.y); pk.u[6] = f2bf(x1.z); pk.u[7] = f2bf(x1.w);
        } else {
            const float* sp = &seq[((b * V + v) * T + (T - 1)) * F + f];
            float4 x0 = *(const float4*)sp, x1 = *(const float4*)(sp + 4);
            float4 mx0 = *(const float4*)&maxval[b * F + f], mx1 = *(const float4*)&maxval[b * F + f + 4];
            float4 mn0 = *(const float4*)&minval[b * F + f], mn1 = *(const float4*)&minval[b * F + f + 4];
            pk.u[0] = f2bf(x0.x * (mx0.x - mn0.x) + mn0.x);
            pk.u[1] = f2bf(x0.y * (mx0.y - mn0.y) + mn0.y);
            pk.u[2] = f2bf(x0.z * (mx0.z - mn0.z) + mn0.z);
            pk.u[3] = f2bf(x0.w * (mx0.w - mn0.w) + mn0.w);
            pk.u[4] = f2bf(x1.x * (mx1.x - mn1.x) + mn1.x);
            pk.u[5] = f2bf(x1.y * (mx1.y - mn1.y) + mn1.y);
            pk.u[6] = f2bf(x1.z * (mx1.z - mn1.z) + mn1.z);
            pk.u[7] = f2bf(x1.w * (mx1.w - mn1.w) + mn1.w);
        }
        *(uint4*)&seqstg[(((size_t)(t * 16 + v)) * 4 + mt * 2 + ks) * 512 + lane * 8] = pk.q;
    }
}

// ---------------------------------------------------------------------------
// Persistent recurrence (R12 loop verbatim; R15 prologue changes):
//  - weight slice converted fp32->bf16 DIRECTLY from W_ih/W_hh into LDS
//    (Wstg global round-trip eliminated)
//  - h1 own-region + c own-elements zeroed here; zero-done published via the
//    bflag family: prologue signals bflag=1, B(t) signals t+2, A(t) waits
//    >= t+1 unconditionally (t=0 wait = zero-done).  No cross-block
//    redundant zeroing -> no stale-zero race (next writer of the region is
//    this same block at t=1, program-ordered).
__global__ __launch_bounds__(256) void k_recur(
    const u16* __restrict__ seqstg,
    const float* __restrict__ W_ih, const float* __restrict__ W_hh,
    const float* __restrict__ w_all, const float* __restrict__ wmax_all,
    const float* __restrict__ b_ih, const float* __restrict__ b_hh,
    float* __restrict__ h0buf, float* __restrict__ h1buf,
    float* __restrict__ c, u16* __restrict__ enc, u16* __restrict__ whstg,
    unsigned* __restrict__ bar) {
    extern __shared__ u16 Wlds[];          // 144 KB weight slice

    int bid = blockIdx.x;
    int v = bid & 15, hk = bid >> 4;
    int tid = threadIdx.x;

    int lane = tid & 63, wvi = tid >> 6;
    int mtw = wvi & 1, hh = wvi >> 1;
    int col = hk * 32 + hh * 16 + (lane & 15);
    int q4 = (lane >> 4) << 2;

    // ---- prologue 1: convert weight slice fp32 -> bf16 fragments in LDS.
    // slot = (nt, ln): row = v*4H + g*512 + hk*32 + hh2*16 + (ln&15),
    // k = ks*32 + (ln>>4)*8.  Wave reads 16 rows x 128B contiguous segments.
    {
#pragma unroll 2
        for (int s = 0; s < 2; ++s) {
            int slot = tid + s * 256;
            int nt = slot >> 6, ln = slot & 63;
            int g = nt >> 1, hh2 = nt & 1;
            int row = v * G4H + g * H + hk * 32 + hh2 * 16 + (ln & 15);
            int kq = (ln >> 4) << 3;
            for (int ks = 0; ks < 18; ++ks) {
                int k = ks * 32 + kq;
                const float* src = (k < F) ? &W_ih[(size_t)row * F + k]
                                           : &W_hh[(size_t)row * H + (k - F)];
                float4 x0 = *(const float4*)src;
                float4 x1 = *(const float4*)(src + 4);
                union { u16 u[8]; uint4 q; } pk;
                pk.u[0] = f2bf(x0.x); pk.u[1] = f2bf(x0.y);
                pk.u[2] = f2bf(x0.z); pk.u[3] = f2bf(x0.w);
                pk.u[4] = f2bf(x1.x); pk.u[5] = f2bf(x1.y);
                pk.u[6] = f2bf(x1.z); pk.u[7] = f2bf(x1.w);
                *(uint4*)&Wlds[(ks * 8 + nt) * 512 + ln * 8] = pk.q;
            }
        }
    }

    // ---- prologue 2: zero own h1 region (rows v, hk-slice; agent) + own c
    {
        int zb = tid >> 3, zq = tid & 7;
        ull* zp = (ull*)&h1buf[(zb * V + v) * H + hk * 32 + zq * 4];
        st_agent(zp, 0ull);
        st_agent(zp + 1, 0ull);
#pragma unroll
        for (int r = 0; r < 4; ++r)
            c[((mtw * 16 + q4 + r) * V + v) * H + col] = 0.0f;
    }

    float bi = b_ih[v * G4H + col] + b_hh[v * G4H + col];
    float bf_ = b_ih[v * G4H + H + col] + b_hh[v * G4H + H + col];
    float bg_ = b_ih[v * G4H + 2 * H + col] + b_hh[v * G4H + 2 * H + col];
    float bo = b_ih[v * G4H + 3 * H + col] + b_hh[v * G4H + 3 * H + col];

    // flag slots: 64B padded.  aflag slot (v*16+hk); bflag slot 256+(hk*16+v)
    unsigned* aslot = bar + (v * 16 + hk) * 16;
    unsigned* bslot = bar + (256 + hk * 16 + v) * 16;
    unsigned* apoll = bar + (v * 16 + (tid & 15)) * 16;          // B-wait family v
    unsigned* bpoll = bar + (256 + hk * 16 + (tid & 15)) * 16;   // A-wait family hk

    // phase-A thread map: thread = (b = tid>>3, colq = tid&7)
    int a_b = tid >> 3;
    int a_cq = tid & 7;
    const int wh_idx = ((((v * 2 + (a_b >> 4)) * 16 + hk) * 64 +
                         (((a_cq >> 1) << 4) + (a_b & 15))) * 8 + (a_cq & 1) * 4);

    __syncthreads();  // W-LDS fill + zero stores drained (waitcnt pre-barrier)
    if (tid == 0) st_agent_u32(bslot, 1u);   // zero-done: A(t=0) gate

    for (int t = 0; t <= T; ++t) {
        int par = t & 1;
        int tm = t < T ? t : (T - 1);
        const float* hin = (t & 1) ? h0buf : h1buf;
        float* hout = (t & 1) ? h1buf : h0buf;

        // ---- pre-wait independent work ------------------------------------
        uint4 s0 = *(const uint4*)&seqstg[(((size_t)(t * 16 + v)) * 4 + mtw * 2 + 0) * 512 + lane * 8];
        uint4 s1 = *(const uint4*)&seqstg[(((size_t)(t * 16 + v)) * 4 + mtw * 2 + 1) * 512 + lane * 8];
        float inv = 1.0f / wmax_all[tm];
        const float* wrow = &w_all[(size_t)tm * (B * V * V) + (a_b * V + v) * V];
        float4 wr0 = *(const float4*)(wrow);
        float4 wr1 = *(const float4*)(wrow + 4);
        float4 wr2 = *(const float4*)(wrow + 8);
        float4 wr3 = *(const float4*)(wrow + 12);
        float cprev[4];
#pragma unroll
        for (int r = 0; r < 4; ++r)
            cprev[r] = c[((mtw * 16 + q4 + r) * V + v) * H + col];

        f32x4 acc[4];
        acc[0][0] = bi;  acc[0][1] = bi;  acc[0][2] = bi;  acc[0][3] = bi;
        acc[1][0] = bf_; acc[1][1] = bf_; acc[1][2] = bf_; acc[1][3] = bf_;
        acc[2][0] = bg_; acc[2][1] = bg_; acc[2][2] = bg_; acc[2][3] = bg_;
        acc[3][0] = bo;  acc[3][1] = bo;  acc[3][2] = bo;  acc[3][3] = bo;
        {   // x-part MFMAs (ks=0,1) are wh-independent
            bf16x8 a0f = mk_bf16x8q(s0);
            bf16x8 a1f = mk_bf16x8q(s1);
#pragma unroll
            for (int g = 0; g < 4; ++g)
                acc[g] = mfma16(a0f, *(const bf16x8*)&Wlds[(0 * 8 + (g * 2 + hh)) * 512 + lane * 8], acc[g]);
#pragma unroll
            for (int g = 0; g < 4; ++g)
                acc[g] = mfma16(a1f, *(const bf16x8*)&Wlds[(1 * 8 + (g * 2 + hh)) * 512 + lane * 8], acc[g]);
        }

        // ---- hop 1: h(t-1) hk-slice ready (t=0: zero-done) ----------------
        if (tid < 16) {
            while (ld_agent_u32(bpoll) < (unsigned)(t + 1)) __builtin_amdgcn_s_sleep(1);
        }
        __syncthreads();

        // ---- phase A: wh[:, v, hk-slice], one (b, 4-col) chunk per thread -
        {
            const ull* hb = (const ull*)&hin[(a_b * V) * H + hk * 32 + a_cq * 4];
            float a0 = 0.f, a1 = 0.f, a2 = 0.f, a3 = 0.f;
            const float wj[16] = {wr0.x, wr0.y, wr0.z, wr0.w, wr1.x, wr1.y, wr1.z, wr1.w,
                                  wr2.x, wr2.y, wr2.z, wr2.w, wr3.x, wr3.y, wr3.z, wr3.w};
#pragma unroll
            for (int j = 0; j < 16; ++j) {
                ull lo = ld_agent(hb + (size_t)j * (H / 2));
                ull hi = ld_agent(hb + (size_t)j * (H / 2) + 1);
                union { ull u; float f[2]; } u0, u1;
                u0.u = lo; u1.u = hi;
                a0 = fmaf(wj[j], u0.f[0], a0);
                a1 = fmaf(wj[j], u0.f[1], a1);
                a2 = fmaf(wj[j], u1.f[0], a2);
                a3 = fmaf(wj[j], u1.f[1], a3);
            }
            union { u16 u[4]; ull q; } pk;
            pk.u[0] = f2bf(a0 * inv); pk.u[1] = f2bf(a1 * inv);
            pk.u[2] = f2bf(a2 * inv); pk.u[3] = f2bf(a3 * inv);
            st_agent((ull*)&whstg[par * WHP + wh_idx], pk.q);
        }
        __syncthreads();  // per-wave drain of wh stores (pre-barrier waitcnt)
        if (tid == 0) st_agent_u32(aslot, (unsigned)(t + 1));

        // ---- hop 2: wh[:, v, :] ready (16 producers A(v,*,t)) -------------
        if (tid < 16) {
            while (ld_agent_u32(apoll) < (unsigned)(t + 1)) __builtin_amdgcn_s_sleep(1);
        }
        __syncthreads();

        // ---- phase B: h-part MFMAs (ks=2..17) -----------------------------
        bf16x8 afr[16];
#pragma unroll
        for (int ksw = 0; ksw < 16; ++ksw) {
            const ull* src = (const ull*)&whstg[par * WHP + (((v * 2 + mtw) * 16 + ksw) * 64 + lane) * 8];
            ull lo = ld_agent(src), hi = ld_agent(src + 1);
            afr[ksw] = mk_bf16x8(lo, hi);
        }
#pragma unroll
        for (int ks = 0; ks < 16; ++ks) {
#pragma unroll
            for (int g = 0; g < 4; ++g) {
                bf16x8 wfr = *(const bf16x8*)&Wlds[((ks + 2) * 8 + (g * 2 + hh)) * 512 + lane * 8];
                acc[g] = mfma16(afr[ks], wfr, acc[g]);
            }
        }

        // ---- epilogue, signal-early: h stores only, then flag (t+2) -------
        float cnv[4], hnv[4];
#pragma unroll
        for (int r = 0; r < 4; ++r) {
            float gi = acc[0][r];
            float gf = acc[1][r];
            float gg = acc[2][r];
            float go = acc[3][r];
            cnv[r] = sigmoidf_(gf) * cprev[r] + sigmoidf_(gi) * tanhf(gg);
            hnv[r] = sigmoidf_(go) * tanhf(cnv[r]);
            int b = mtw * 16 + q4 + r;
            st_agent_f(&hout[(b * V + v) * H + col], hnv[r]);
        }
        if (t < T) {
            __syncthreads();  // per-wave drain of h stores
            if (tid == 0) st_agent_u32(bslot, (unsigned)(t + 2));
        }

        // ---- post-signal: enc + c (off the critical path, PLAIN stores) ---
#pragma unroll
        for (int r = 0; r < 4; ++r) {
            int b = mtw * 16 + q4 + r;
            c[(b * V + v) * H + col] = cnv[r];
            if (t < T) enc[((size_t)(b * V + v) * T + t) * H + col] = f2bf(hnv[r]);
        }
    }
}

// ---------------------------------------------------------------------------
// Fused tail (R14 verbatim): attn + soft + out.  enc/h via kernel boundary;
// ctx/hsoft (alias w_all, dead after recur) via agent stores + flag hops.
__global__ __launch_bounds__(256) void k_tail(
    const u16* __restrict__ enc, const float* __restrict__ hfin,
    const float* __restrict__ mask, const float* __restrict__ soft_W,
    const float* __restrict__ soft_b, const float* __restrict__ out_W,
    const float* __restrict__ out_b, float* __restrict__ ctx,
    float* __restrict__ hsoft, float* __restrict__ out,
    unsigned* __restrict__ bar) {
    __shared__ float hs[H];
    __shared__ float scal[2 * T];
    __shared__ float sA[32][36];
    __shared__ float sW2[32][36];

    int bid = blockIdx.x;
    int tid = threadIdx.x;
    int lane = tid & 63, wvi = tid >> 6;

    // ---- attn: 2 units per block: (b = bid>>4 + u*16, v = bid&15) ---------
    for (int u = 0; u < 2; ++u) {
        int ab = (bid >> 4) + u * 16;
        int av = bid & 15;
        const u16* encb = enc + ((size_t)(ab * V + av) * T) * H;
        {   // hs <- final h (plain)
            float2 q = *(const float2*)(hfin + (ab * V + av) * H + tid * 2);
            hs[tid * 2] = q.x; hs[tid * 2 + 1] = q.y;
        }
        __syncthreads();
        // scores: wave handles tt stride-4; lane owns cols [lane*8, lane*8+8)
        for (int tt = wvi; tt < T; tt += 4) {
            uint4 x = *(const uint4*)(encb + tt * H + lane * 8);
            union { uint4 q; u16 s[8]; } e; e.q = x;
            const float* hq = &hs[lane * 8];
            float p = bf2f(e.s[0]) * hq[0] + bf2f(e.s[1]) * hq[1]
                    + bf2f(e.s[2]) * hq[2] + bf2f(e.s[3]) * hq[3]
                    + bf2f(e.s[4]) * hq[4] + bf2f(e.s[5]) * hq[5]
                    + bf2f(e.s[6]) * hq[6] + bf2f(e.s[7]) * hq[7];
            for (int off = 32; off; off >>= 1) p += __shfl_down(p, off, 64);
            if (lane == 0) scal[tt] = p;
        }
        __syncthreads();
        if (tid < 64) {
            float m_t = mask[(ab * V + av) * T + tid];
            float s = scal[tid] * m_t;
            float mx = s;
            for (int off = 32; off; off >>= 1) mx = fmaxf(mx, __shfl_xor(mx, off, 64));
            float e = __expf(s - mx);
            float sum = e;
            for (int off = 32; off; off >>= 1) sum += __shfl_xor(sum, off, 64);
            scal[T + tid] = e / sum;
        }
        __syncthreads();
        // ctx: threads 0..127, thread g -> cols [4g, 4g+4); agent stores
        if (tid < 128) {
            float a0 = 0.f, a1 = 0.f, a2 = 0.f, a3 = 0.f;
            for (int tt = 0; tt < T; ++tt) {
                ull x = *(const ull*)(encb + tt * H + tid * 4);
                union { ull u; u16 s[4]; } q; q.u = x;
                float al = scal[T + tt];
                a0 = fmaf(al, bf2f(q.s[0]), a0);
                a1 = fmaf(al, bf2f(q.s[1]), a1);
                a2 = fmaf(al, bf2f(q.s[2]), a2);
                a3 = fmaf(al, bf2f(q.s[3]), a3);
            }
            float* cp = ctx + (ab * V + av) * H + tid * 4;
            union { float f[2]; ull u; } q0, q1;
            q0.f[0] = a0; q0.f[1] = a1; q1.f[0] = a2; q1.f[1] = a3;
            st_agent((ull*)cp, q0.u);
            st_agent((ull*)cp + 1, q1.u);
        }
        __syncthreads();
    }
    __syncthreads();  // drain ctx stores (all waves)
    if (tid == 0) st_agent_u32(bar + (768 + bid) * 16, 1u);

    // ---- soft: block -> (v = bid&15, h0 = (bid>>4)*32) --------------------
    {
        int sv = bid & 15;
        int h0 = (bid >> 4) * 32;
        if (tid < 16) {  // wait ctx of all 32 b for vessel sv (16 attn blocks)
            const unsigned* cs = bar + (768 + tid * 16 + sv) * 16;
            while (ld_agent_u32(cs) < 1u) __builtin_amdgcn_s_sleep(1);
        }
        __syncthreads();

        int cg = tid & 31, rg = tid >> 5;
        float* sAf = &sA[0][0];
        float* sWf = &sW2[0][0];
        float accs[4] = {0.f, 0.f, 0.f, 0.f};
        int arow = tid >> 3, akq = tid & 7;
        float4 areg, wreg;
        {
            int k = akq * 4;
            const float* src = (arow < 16) ? ctx : hfin;
            int bsrc = 2 * (arow & 15) + (k >= H ? 1 : 0);
            const float* sp = &src[(bsrc * V + sv) * H + (k & (H - 1))];
            ull l0 = ld_agent((const ull*)sp), l1 = ld_agent((const ull*)sp + 1);
            union { ull u[2]; float4 f; } q; q.u[0] = l0; q.u[1] = l1;
            areg = q.f;
            wreg = *(const float4*)&soft_W[(sv * H + h0 + arow) * (2 * H) + k];
        }
        for (int kc = 0; kc < 2 * H; kc += 32) {
            __syncthreads();
            *(float4*)&sAf[arow * 36 + akq * 4] = areg;
            *(float4*)&sWf[arow * 36 + akq * 4] = wreg;
            __syncthreads();
            if (kc + 32 < 2 * H) {
                int k = kc + 32 + akq * 4;
                const float* src = (arow < 16) ? ctx : hfin;
                int bsrc = 2 * (arow & 15) + (k >= H ? 1 : 0);
                const float* sp = &src[(bsrc * V + sv) * H + (k & (H - 1))];
                ull l0 = ld_agent((const ull*)sp), l1 = ld_agent((const ull*)sp + 1);
                union { ull u[2]; float4 f; } q; q.u[0] = l0; q.u[1] = l1;
                areg = q.f;
                wreg = *(const float4*)&soft_W[(sv * H + h0 + arow) * (2 * H) + kc + 32 + akq * 4];
            }
#pragma unroll
            for (int k4 = 0; k4 < 8; ++k4) {
                float4 wv = *(const float4*)&sWf[cg * 36 + k4 * 4];
                float4 a0 = *(const float4*)&sAf[(rg * 4 + 0) * 36 + k4 * 4];
                float4 a1 = *(const float4*)&sAf[(rg * 4 + 1) * 36 + k4 * 4];
                float4 a2 = *(const float4*)&sAf[(rg * 4 + 2) * 36 + k4 * 4];
                float4 a3 = *(const float4*)&sAf[(rg * 4 + 3) * 36 + k4 * 4];
                accs[0] += a0.x * wv.x + a0.y * wv.y + a0.z * wv.z + a0.w * wv.w;
                accs[1] += a1.x * wv.x + a1.y * wv.y + a1.z * wv.z + a1.w * wv.w;
                accs[2] += a2.x * wv.x + a2.y * wv.y + a2.z * wv.z + a2.w * wv.w;
                accs[3] += a3.x * wv.x + a3.y * wv.y + a3.z * wv.z + a3.w * wv.w;
            }
        }
        float bb = soft_b[sv * H + h0 + cg];
#pragma unroll
        for (int r = 0; r < 4; ++r) {
            int row = rg * 4 + r;
            st_agent_f(&hsoft[(row * V + sv) * H + h0 + cg], tanhf(accs[r] + bb));
        }
    }
    __syncthreads();  // drain hsoft stores
    if (tid == 0) st_agent_u32(bar + (1024 + bid) * 16, 1u);

    // ---- out: waves 0,1 -> units (b = bid>>4 + wvi*16, v = bid&15) --------
    {
        int ov = bid & 15;
        if (tid < 16) {  // wait hsoft of all 16 h0 slices for vessel ov
            const unsigned* ss = bar + (1024 + tid * 16 + ov) * 16;
            while (ld_agent_u32(ss) < 1u) __builtin_amdgcn_s_sleep(1);
        }
        __syncthreads();
        if (wvi < 2) {
            int ob = (bid >> 4) + wvi * 16;
            const float* hbp = hsoft + (ob * V + ov) * H + lane * 8;
            ull q0 = ld_agent((const ull*)hbp);
            ull q1 = ld_agent((const ull*)hbp + 1);
            ull q2 = ld_agent((const ull*)hbp + 2);
            ull q3 = ld_agent((const ull*)hbp + 3);
            union { ull u[4]; float f[8]; } hv;
            hv.u[0] = q0; hv.u[1] = q1; hv.u[2] = q2; hv.u[3] = q3;
            float p[4] = {0.f, 0.f, 0.f, 0.f};
#pragma unroll
            for (int o = 0; o < 4; ++o) {
                const float* wp = &out_W[o * H + lane * 8];
#pragma unroll
                for (int j = 0; j < 8; ++j) p[o] += hv.f[j] * wp[j];
            }
#pragma unroll
            for (int o = 0; o < 4; ++o) {
                float s = p[o];
                for (int off = 32; off; off >>= 1) s += __shfl_down(s, off, 64);
                if (lane == 0) {
                    float val = s + out_b[o];
                    out[(ob * V + ov) * 4 + o] = val > 0.0f ? val : 0.0f;
                }
            }
        }
    }
}

// ---------------------------------------------------------------------------
extern "C" void kernel_launch(void* const* d_in, const int* in_sizes, int n_in,
                              void* d_out, int out_size, void* d_ws, size_t ws_size,
                              hipStream_t stream) {
    const float* seq = (const float*)d_in[0];
    const float* dist = (const float*)d_in[1];
    const int* rb = (const int*)d_in[2];
    const int* cog = (const int*)d_in[3];
    const float* mask = (const float*)d_in[4];
    const float* maxval = (const float*)d_in[5];
    const float* minval = (const float*)d_in[6];
    const float* W_ih = (const float*)d_in[7];
    const float* W_hh = (const float*)d_in[8];
    const float* b_ih = (const float*)d_in[9];
    const float* b_hh = (const float*)d_in[10];
    const float* domain = (const float*)d_in[11];
    const float* soft_W = (const float*)d_in[12];
    const float* soft_b = (const float*)d_in[13];
    const float* out_W = (const float*)d_in[14];
    const float* out_b = (const float*)d_in[15];

    float* ws = (float*)d_ws;
    float* h0buf = ws + OFF_H0;
    float* h1buf = ws + OFF_H1;
    float* c = ws + OFF_C;
    unsigned* bar = (unsigned*)(ws + OFF_CNT);
    float* w_all = ws + OFF_WALL;
    float* ctx = ws + OFF_CTX;      // alias (w_all dead after k_recur)
    float* hsoft = ws + OFF_HSOFT;  // alias
    float* wmax_all = ws + OFF_WMAX;
    u16* whstg = (u16*)(ws + OFF_WHSTG);
    u16* seqstg = (u16*)(ws + OFF_SEQSTG);
    u16* enc = (u16*)(ws + OFF_ENC);

    // allow >64 KB dynamic LDS for k_recur (idempotent; capture-safe host call)
    (void)hipFuncSetAttribute((const void*)k_recur,
                              hipFuncAttributeMaxDynamicSharedMemorySize, WLDS_BYTES);

    // prep: zero flag slots + hw_all + seqstg (wconv/zeroing now in k_recur)
    k_prep<<<NZB + NHW + NSS, 256, 0, stream>>>(
        ws, dist, rb, cog, mask, domain, w_all, wmax_all,
        seq, maxval, minval, seqstg);

    // whole recurrence (64 encoder steps + 1 decoder step) in one launch
    k_recur<<<256, 256, WLDS_BYTES, stream>>>(seqstg, W_ih, W_hh, w_all,
                                              wmax_all, b_ih, b_hh, h0buf,
                                              h1buf, c, enc, whstg, bar);

    // fused attn + soft + out (final h is in h0buf; t=64 writes buf[0])
    k_tail<<<256, 256, 0, stream>>>(enc, h0buf, mask, soft_W, soft_b,
                                    out_W, out_b, ctx, hsoft,
                                    (float*)d_out, bar);
}